// Round 3
// baseline (523.188 us; speedup 1.0000x reference)
//
#include <hip/hip_runtime.h>
#include <hip/hip_bf16.h>

// Problem constants (AlignmentMatrix): B=128, L1=1024, L2=128, H2=600
static constexpr int Bn  = 128;
static constexpr int L1c = 1024;
static constexpr int L2c = 128;
static constexpr int H2c = 600;

#define BM 128
#define BN 128
#define BK 64
#define LDK 72              // BK + 8 pad shorts; row stride 144 B (16B-aligned, non-pow2 banks)
static constexpr int NCHUNK = (H2c + BK - 1) / BK;   // 10 (last chunk: 24 valid cols, zero-padded)

typedef __attribute__((ext_vector_type(8))) __bf16 bf16x8;
typedef __attribute__((ext_vector_type(4))) float  f32x4;

__device__ __forceinline__ unsigned short f2bf(float f) {
    // round-to-nearest-even f32 -> bf16
    unsigned int u = __float_as_uint(f);
    u += 0x7FFFu + ((u >> 16) & 1u);
    return (unsigned short)(u >> 16);
}

// 512 threads = 8 waves in a 4x2 grid of 32x64 sub-tiles.
// ROUND-3 structure: double-buffered LDS + ONE barrier per chunk; chunk-k+1
// global loads reissued inside the convert loop right after each register's
// last use (same regs -> no extra liveness). Load-latency window becomes
// (rest of convert) + barrier + MFMA ~ 1000+ cyc, covering ~900 cyc HBM.
__global__ __launch_bounds__(512, 4)
void align_kernel(const float* __restrict__ ctx, const float* __restrict__ asp,
                  const float* __restrict__ w_u, float* __restrict__ out)
{
    __shared__ unsigned short As[2][BM * LDK];   // 2 x 18432 B, (ctx*w3) in bf16
    __shared__ unsigned short Bs[2][BN * LDK];   // 2 x 18432 B, asp in bf16
    __shared__ float sA[BM];                     // s_ctx for block rows
    __shared__ float sB[BN];                     // s_asp for block cols

    // XCD-bijective decode (measured neutral; kept -- harmless, tiny L2 upside).
    const int id   = blockIdx.x;
    const int xcd  = id & 7;
    const int slot = id >> 3;
    const int rt   = slot & 7;    // row tile 0..7
    const int bq   = slot >> 3;   // 0..15
    const int b    = xcd + 8 * bq;
    const int rowBase = rt * BM;

    const int tid  = threadIdx.x;
    const int lane = tid & 63;
    const int wave = tid >> 6;     // 0..7
    const int wm   = wave >> 1;    // 0..3: 32-row band
    const int wn   = wave & 1;     // 0..1: 64-col half
    const int quad = lane >> 4;
    const int l15  = lane & 15;

    const float* ctx_base = ctx + ((size_t)b * L1c + rowBase) * H2c;
    const float* asp_base = asp + (size_t)b * L2c * H2c;
    const float* w1 = w_u;
    const float* w2 = w_u + H2c;
    const float* w3 = w_u + 2 * H2c;

    // staging: thread (srow,scg) covers rows {srow+32i, i<4}, cols [scg*4, scg*4+3]
    const int srow = tid >> 4;     // 0..31
    const int scg  = tid & 15;     // 0..15
    const int d0   = scg * 4;      // 0..60

    f32x4 acc[2][4];
    const f32x4 zero4 = {0.f, 0.f, 0.f, 0.f};
#pragma unroll
    for (int i = 0; i < 2; i++)
#pragma unroll
        for (int j = 0; j < 4; j++) acc[i][j] = zero4;

    float sctxp[4], saspp[4];
#pragma unroll
    for (int i = 0; i < 4; i++) { sctxp[i] = 0.f; saspp[i] = 0.f; }

    float4 Apre[4], Bpre[4], w1v, w2v, w3v;

    // ---- prologue: load chunk 0 (always fully valid) ----
    {
        const int kd = d0;
        w1v = *(const float4*)(w1 + kd);
        w2v = *(const float4*)(w2 + kd);
        w3v = *(const float4*)(w3 + kd);
#pragma unroll
        for (int i = 0; i < 4; i++) {
            const int row = srow + i * 32;
            Apre[i] = *(const float4*)(ctx_base + row * H2c + kd);
            Bpre[i] = *(const float4*)(asp_base + row * H2c + kd);
        }
    }

    for (int kc = 0; kc < NCHUNK; kc++) {
        unsigned short* Asw = As[kc & 1];
        unsigned short* Bsw = Bs[kc & 1];
        const int  kd    = (kc + 1) * BK + d0;
        const bool pref  = (kc + 1 < NCHUNK);
        const bool valid = pref && (kd < H2c);   // whole float4 valid or not (H2c%4==0)
        const float4 z4  = make_float4(0.f, 0.f, 0.f, 0.f);

        // ---- convert + write chunk kc from regs; fuse rank-1 partial dots;
        //      reissue each register's chunk-k+1 load right after its last use ----
#pragma unroll
        for (int i = 0; i < 4; i++) {
            const int row = srow + i * 32;
            float4 av = Apre[i];
            if (pref) Apre[i] = valid ? *(const float4*)(ctx_base + row * H2c + kd) : z4;
            sctxp[i] += av.x * w1v.x + av.y * w1v.y + av.z * w1v.z + av.w * w1v.w;
            ushort4 pv;
            pv.x = f2bf(av.x * w3v.x);
            pv.y = f2bf(av.y * w3v.y);
            pv.z = f2bf(av.z * w3v.z);
            pv.w = f2bf(av.w * w3v.w);
            *(ushort4*)(&Asw[row * LDK + d0]) = pv;

            float4 bv = Bpre[i];
            if (pref) Bpre[i] = valid ? *(const float4*)(asp_base + row * H2c + kd) : z4;
            saspp[i] += bv.x * w2v.x + bv.y * w2v.y + bv.z * w2v.z + bv.w * w2v.w;
            ushort4 qv;
            qv.x = f2bf(bv.x);
            qv.y = f2bf(bv.y);
            qv.z = f2bf(bv.z);
            qv.w = f2bf(bv.w);
            *(ushort4*)(&Bsw[row * LDK + d0]) = qv;
        }
        // w vectors: last use was above; reload for chunk k+1 (tiny, L1-hot)
        if (pref) {
            w1v = valid ? *(const float4*)(w1 + kd) : z4;
            w2v = valid ? *(const float4*)(w2 + kd) : z4;
            w3v = valid ? *(const float4*)(w3 + kd) : z4;
        }

        __syncthreads();   // staged tile visible; prior-chunk MFMA readers all done

        // ---- MFMA: 2 k-steps of 32; wave computes 32x64 as 2x4 of 16x16 ----
        const unsigned short* Asr = As[kc & 1];
        const unsigned short* Bsr = Bs[kc & 1];
#pragma unroll
        for (int ks = 0; ks < 2; ks++) {
            const int kk = ks * 32 + quad * 8;   // A/B frag: [m=lane&15][k=quad*8+j]
            bf16x8 afr[2], bfr[4];
#pragma unroll
            for (int t = 0; t < 2; t++)
                afr[t] = *(const bf16x8*)(&Asr[(wm * 32 + t * 16 + l15) * LDK + kk]);
#pragma unroll
            for (int t = 0; t < 4; t++)
                bfr[t] = *(const bf16x8*)(&Bsr[(wn * 64 + t * 16 + l15) * LDK + kk]);
#pragma unroll
            for (int tm = 0; tm < 2; tm++)
#pragma unroll
                for (int tn = 0; tn < 4; tn++)
                    acc[tm][tn] = __builtin_amdgcn_mfma_f32_16x16x32_bf16(
                        afr[tm], bfr[tn], acc[tm][tn], 0, 0, 0);
        }
        // no second barrier: WAR on buf (kc+1)&1 is protected by the next
        // iteration's barrier (every wave past bar_k has finished mfma_{k-1}).
    }

    // ---- reduce s_ctx / s_asp partials (reuse As[0] as scratch: 128x16 f32 = 8 KB)
    //      safe: last reads of As[0] were mfma_8, complete before bar_9 for all waves;
    //      concurrent mfma_9 reads As[1]/Bs[1] only. ----
    float* red = (float*)As[0];
#pragma unroll
    for (int i = 0; i < 4; i++) red[(srow + i * 32) * 16 + scg] = sctxp[i];
    __syncthreads();
    if (tid < BM) {
        float s = 0.f;
#pragma unroll
        for (int c = 0; c < 16; c++) s += red[tid * 16 + c];
        sA[tid] = s;
    }
    __syncthreads();
#pragma unroll
    for (int i = 0; i < 4; i++) red[(srow + i * 32) * 16 + scg] = saspp[i];
    __syncthreads();
    if (tid < BN) {
        float s = 0.f;
#pragma unroll
        for (int c = 0; c < 16; c++) s += red[tid * 16 + c];
        sB[tid] = s;
    }
    __syncthreads();

    // ---- epilogue: D mapping col=lane&15, row=quad*4+reg; add s_ctx[m] + s_asp[n] ----
    float* out_base = out + ((size_t)b * L1c + rowBase) * L2c;
#pragma unroll
    for (int tm = 0; tm < 2; tm++) {
#pragma unroll
        for (int tn = 0; tn < 4; tn++) {
            const int col = wn * 64 + tn * 16 + l15;
            const float sbv = sB[col];
#pragma unroll
            for (int r = 0; r < 4; r++) {
                const int m = wm * 32 + tm * 16 + quad * 4 + r;
                out_base[(size_t)m * L2c + col] = acc[tm][tn][r] + sA[m] + sbv;
            }
        }
    }
}

extern "C" void kernel_launch(void* const* d_in, const int* in_sizes, int n_in,
                              void* d_out, int out_size, void* d_ws, size_t ws_size,
                              hipStream_t stream) {
    // inputs: [0]=batch_size (int scalar), [1]=ctx f32, [2]=asp f32, [3]=w_u f32
    const float* ctx = (const float*)d_in[1];
    const float* asp = (const float*)d_in[2];
    const float* w_u = (const float*)d_in[3];
    float* out = (float*)d_out;

    dim3 grid(L1c / BM * Bn);   // 1024 blocks flat; XCD-bijective decode in-kernel
    align_kernel<<<grid, 512, 0, stream>>>(ctx, asp, w_u, out);
}